// Round 14
// baseline (65.440 us; speedup 1.0000x reference)
//
#include <hip/hip_runtime.h>
#include <float.h>

// EuclideanCodebook R14: the TLP round — 16 waves/CU (4/SIMD), every prior
// round ran at ~6/CU (1.5/SIMD) and starved the matrix pipe on dep-latency.
//  - 512-thr blocks (8 waves), BROWS=128, grid=512 -> 2 independent blocks/CU.
//  - wave = 32 rows (2 rt) x 16 codes (nt split); 8 ds_read : 24 MFMA.
//  - 6 independent acc chains (split by f16-split pass; reuse distance 6).
//  - __launch_bounds__(512,4) caps regs at 128 -> 4 waves/SIMD.
//  - CH=32 dbuf (32KB), exact vmcnt(2) protocol, LDS 39KB.
// Core numerics unchanged (verified absmax-0): 16x16x32 f16-split, fp32 acc,
// score = 2*dot - e^2 (x^2 dropped), first-index tie-break everywhere.
// ws: [0: esq 4KB | 4096: fragment-ordered codebook image 512KB]

#define Cdim        128
#define KCODES      1024
#define CH          32
#define NCH         32
#define BROWS       128       // 4 row-groups x 32 rows; wave pairs split codes
#define THREADS     512
#define IMG_OFF     4096
#define CHUNK_BYTES 16384     // [nt0: hi 4K, lo 4K | nt1: hi 4K, lo 4K]

typedef _Float16 f16;
typedef __attribute__((ext_vector_type(8))) _Float16 f16x8;
typedef __attribute__((ext_vector_type(4))) float    f32x4;

#define MFMA16(A, B, C) __builtin_amdgcn_mfma_f32_16x16x32_f16((A), (B), (C), 0, 0, 0)

// ---------------- e_sq pre-pass (exact fp32) ----------------
__global__ __launch_bounds__(256) void esq_kernel(const float* __restrict__ embed,
                                                  float* __restrict__ esq, int K) {
    int gid  = blockIdx.x * blockDim.x + threadIdx.x;
    int code = gid >> 6;
    int lane = threadIdx.x & 63;
    if (code >= K) return;
    float2 v = ((const float2*)(embed + (size_t)code * Cdim))[lane];
    float  s = fmaf(v.x, v.x, v.y * v.y);
    #pragma unroll
    for (int m = 32; m >= 1; m >>= 1) s += __shfl_xor(s, m, 64);
    if (lane == 0) esq[code] = s;
}

__device__ __forceinline__ void cvt8s(float4 a, float4 b, float scale,
                                      f16x8& h, f16x8& lo) {
    float v[8] = {a.x, a.y, a.z, a.w, b.x, b.y, b.z, b.w};
    #pragma unroll
    for (int i = 0; i < 8; ++i) {
        float s = v[i] * scale;
        f16 hh = (f16)s;
        h[i]  = hh;
        lo[i] = (f16)(s - (float)hh);
    }
}

// ---- codebook -> 16x16x32-fragment image, wave-linear lane order ----
// A-frag: lane l holds e[base16 + (l&15)][ks*32 + (l>>4)*8 .. +8]
// hi: IMG_OFF + ch*16384 + nt*8192 + ks*1024 + ((l>>4... via kseg)*16+lr)*16; lo +4096
__global__ __launch_bounds__(256) void bconv_kernel(const float* __restrict__ embed,
                                                    char* __restrict__ ws) {
    int t    = blockIdx.x * 256 + threadIdx.x;   // 16384 threads
    int code = t >> 4;
    int seg  = t & 15;
    int ks   = seg >> 2;
    int kseg = seg & 3;
    int ch = code >> 5, nt = (code >> 4) & 1, lr = code & 15;
    const float4* p = (const float4*)(embed + (size_t)code * Cdim + ks * 32 + kseg * 8);
    f16x8 h, lo;
    cvt8s(p[0], p[1], 1.0f, h, lo);
    size_t base = (size_t)IMG_OFF + (size_t)ch * CHUNK_BYTES
                + nt * 8192 + ks * 1024 + (kseg * 16 + lr) * 16;
    *(f16x8*)(ws + base)        = h;
    *(f16x8*)(ws + base + 4096) = lo;
}

// ---------------- async global->LDS 16B ----------------
__device__ __forceinline__ void gll16(const void* g, void* l) {
    __builtin_amdgcn_global_load_lds(
        (const __attribute__((address_space(1))) unsigned int*)g,
        (__attribute__((address_space(3))) unsigned int*)l, 16, 0, 0);
}

__global__ __launch_bounds__(THREADS, 4) void vq_kernel(
    const float* __restrict__ x, const float* __restrict__ embed,
    const char* __restrict__ ws, float* __restrict__ outq,
    float* __restrict__ outi) {

    __shared__ __align__(16) char  Bb[2][CHUNK_BYTES];   // 32KB dbuf
    __shared__ __align__(16) float esq_lds[KCODES];      // 4KB
    __shared__ float mrgv[2][BROWS];
    __shared__ int   mrgi[2][BROWS];
    __shared__ int   winners[BROWS];

    const int tid  = threadIdx.x;
    const int wid  = tid >> 6;          // wave 0..7
    const int l    = tid & 63;
    const int lr   = l & 15;            // x-row within 16-tile
    const int lg   = l >> 4;            // k-seg (in) / code-subrow (out)
    const int wr   = wid >> 1;          // row group (32 rows)
    const int nt   = wid & 1;           // code half of each chunk (16 codes)
    const int row0 = blockIdx.x * BROWS;

    // ---- prologue DMA: chunk 0 (2KB/wave) + esq (waves 0..3) ----
    {
        const char* src = ws + IMG_OFF + wid * 1024 + (size_t)l * 16;
        gll16(src,        &Bb[0][wid * 1024]);
        gll16(src + 8192, &Bb[0][wid * 1024 + 8192]);
        if (wid < 4)
            gll16(ws + wid * 1024 + (size_t)l * 16, (char*)esq_lds + wid * 1024);
    }

    // ---- x rows -> B-fragments (2*xh, 2*xl): 2 rt-tiles of 16 rows ----
    f16x8 bxh[2][4], bxl[2][4];
    #pragma unroll
    for (int rt = 0; rt < 2; ++rt) {
        const float* xr = x + (size_t)(row0 + wr * 32 + rt * 16 + lr) * Cdim + lg * 8;
        #pragma unroll
        for (int ks = 0; ks < 4; ++ks) {
            float4 v0 = *(const float4*)(xr + ks * 32);
            float4 v1 = *(const float4*)(xr + ks * 32 + 4);
            cvt8s(v0, v1, 2.0f, bxh[rt][ks], bxl[rt][ks]);
        }
    }

    float best[2] = {-FLT_MAX, -FLT_MAX};
    int   bidx[2] = {0, 0};

    #pragma unroll 1
    for (int ch = 0; ch < NCH; ++ch) {
        const int cur = ch & 1, nxt = cur ^ 1;

        __builtin_amdgcn_s_barrier();            // all done reading Bb[nxt]
        if (ch + 1 < NCH) {                      // prefetch chunk ch+1 (2 loads)
            const char* src = ws + IMG_OFF + (size_t)(ch + 1) * CHUNK_BYTES
                            + wid * 1024 + (size_t)l * 16;
            gll16(src,        &Bb[nxt][wid * 1024]);
            gll16(src + 8192, &Bb[nxt][wid * 1024 + 8192]);
            asm volatile("s_waitcnt vmcnt(2)" ::: "memory");   // chunk ch staged
        } else {
            asm volatile("s_waitcnt vmcnt(0)" ::: "memory");
        }
        __builtin_amdgcn_s_barrier();            // chunk ch visible block-wide

        // 6 independent accumulator chains (by pass x rt); reuse distance 6
        f32x4 a1[2], a2[2], a3[2];
        #pragma unroll
        for (int rt = 0; rt < 2; ++rt) {
            a1[rt] = (f32x4){0.f, 0.f, 0.f, 0.f};
            a2[rt] = (f32x4){0.f, 0.f, 0.f, 0.f};
            a3[rt] = (f32x4){0.f, 0.f, 0.f, 0.f};
        }

        const char* bb = &Bb[cur][nt * 8192 + (size_t)l * 16];
        #pragma unroll
        for (int ks = 0; ks < 4; ++ks) {
            f16x8 eh = *(const f16x8*)(bb + ks * 1024);
            f16x8 el = *(const f16x8*)(bb + 4096 + ks * 1024);
            __builtin_amdgcn_s_setprio(1);
            a1[0] = MFMA16(eh, bxh[0][ks], a1[0]);
            a1[1] = MFMA16(eh, bxh[1][ks], a1[1]);
            a2[0] = MFMA16(eh, bxl[0][ks], a2[0]);
            a2[1] = MFMA16(eh, bxl[1][ks], a2[1]);
            a3[0] = MFMA16(el, bxh[0][ks], a3[0]);
            a3[1] = MFMA16(el, bxh[1][ks], a3[1]);
            __builtin_amdgcn_s_setprio(0);
        }

        // scoring: s = 2*dot - e^2; codes cb+j ascend, strict > (first wins)
        const int cb = ch * CH + nt * 16 + lg * 4;
        float4 e4 = *(const float4*)&esq_lds[cb];
        #pragma unroll
        for (int rt = 0; rt < 2; ++rt)
            #pragma unroll
            for (int j = 0; j < 4; ++j) {
                float s = ((a1[rt][j] + a2[rt][j]) + a3[rt][j]) - ((const float*)&e4)[j];
                if (s > best[rt]) { best[rt] = s; bidx[rt] = cb + j; }
            }
    }

    // ---- reduce over lg (lanes lr, lr+16, lr+32, lr+48 share each row) ----
    #pragma unroll
    for (int rt = 0; rt < 2; ++rt) {
        float bs = best[rt]; int bi = bidx[rt];
        #pragma unroll
        for (int m = 16; m <= 32; m <<= 1) {
            float vs = __shfl_xor(bs, m, 64);
            int   vi = __shfl_xor(bi, m, 64);
            if (vs > bs || (vs == bs && vi < bi)) { bs = vs; bi = vi; }
        }
        if (lg == 0) {
            mrgv[nt][wr * 32 + rt * 16 + lr] = bs;
            mrgi[nt][wr * 32 + rt * 16 + lr] = bi;
        }
    }
    __syncthreads();
    if (tid < BROWS) {
        float v0 = mrgv[0][tid]; int i0 = mrgi[0][tid];
        float v1 = mrgv[1][tid]; int i1 = mrgi[1][tid];
        int bi = (v1 > v0 || (v1 == v0 && i1 < i0)) ? i1 : i0;
        winners[tid] = bi;
        outi[row0 + tid] = (float)bi;
    }
    __syncthreads();

    // ---- gather quantized = embed[winner] (exact fp32 copy) ----
    #pragma unroll
    for (int i = 0; i < 8; ++i) {
        int pos = i * THREADS + tid;
        int r = pos >> 5, c4 = pos & 31;
        int idx = winners[r];
        float4 v = ((const float4*)(embed + (size_t)idx * Cdim))[c4];
        ((float4*)(outq + (size_t)(row0 + r) * Cdim))[c4] = v;
    }
}

extern "C" void kernel_launch(void* const* d_in, const int* in_sizes, int n_in,
                              void* d_out, int out_size, void* d_ws, size_t ws_size,
                              hipStream_t stream) {
    const float* x     = (const float*)d_in[0];
    const float* embed = (const float*)d_in[1];
    const int M = in_sizes[0] / Cdim;   // 65536
    const int K = in_sizes[1] / Cdim;   // 1024
    float* outq = (float*)d_out;
    float* outi = outq + (size_t)M * Cdim;

    esq_kernel <<<K / 4, 256, 0, stream>>>(embed, (float*)d_ws, K);
    bconv_kernel<<<64, 256, 0, stream>>>(embed, (char*)d_ws);
    vq_kernel  <<<M / BROWS, THREADS, 0, stream>>>(x, embed, (const char*)d_ws,
                                                   outq, outi);
}

// Round 15
// 61.624 us; speedup vs baseline: 1.0619x; 1.0619x over previous
//
#include <hip/hip_runtime.h>
#include <float.h>

// EuclideanCodebook R15: R9 (the measured best, 55.3us) with two trims:
//  (1) no s_setprio (m190: negative on lockstep barrier-synced GEMM loops);
//  (2) scoring via pairwise index-aware merge TREE (dep depth 8 -> 4) on the
//      critical path between the chunk's last MFMA and the barrier.
// Core identical to R9: 16x16x32 f16-split (3 passes into ONE acc per tile,
// 8 independent chains), wave-linear fragment image (conflict-free identity
// ds_read), CH=64 DMA dbuf via global_load_lds, counted vmcnt(8), 2 blocks/CU.
// score = 2*dot - e^2 (x^2 dropped: per-row constant, argmax-invariant).
// ws: [0: esq 4KB | 4096: fragment-ordered codebook image 512KB]

#define Cdim        128
#define KCODES      1024
#define CH          64
#define NCH         16
#define BROWS       128       // 2 row-groups x 64 rows; wave pair splits codes
#define THREADS     256
#define IMG_OFF     4096
#define CHUNK_BYTES 32768     // [hi: (ctg*4+ks)*1KB x16 | lo: +16KB]

typedef _Float16 f16;
typedef __attribute__((ext_vector_type(8))) _Float16 f16x8;
typedef __attribute__((ext_vector_type(4))) float    f32x4;

#define MFMA16(A, B, C) __builtin_amdgcn_mfma_f32_16x16x32_f16((A), (B), (C), 0, 0, 0)

// ---------------- e_sq pre-pass (exact fp32) ----------------
__global__ __launch_bounds__(256) void esq_kernel(const float* __restrict__ embed,
                                                  float* __restrict__ esq, int K) {
    int gid  = blockIdx.x * blockDim.x + threadIdx.x;
    int code = gid >> 6;
    int lane = threadIdx.x & 63;
    if (code >= K) return;
    float2 v = ((const float2*)(embed + (size_t)code * Cdim))[lane];
    float  s = fmaf(v.x, v.x, v.y * v.y);
    #pragma unroll
    for (int m = 32; m >= 1; m >>= 1) s += __shfl_xor(s, m, 64);
    if (lane == 0) esq[code] = s;
}

__device__ __forceinline__ void cvt8s(float4 a, float4 b, float scale,
                                      f16x8& h, f16x8& lo) {
    float v[8] = {a.x, a.y, a.z, a.w, b.x, b.y, b.z, b.w};
    #pragma unroll
    for (int i = 0; i < 8; ++i) {
        float s = v[i] * scale;
        f16 hh = (f16)s;
        h[i]  = hh;
        lo[i] = (f16)(s - (float)hh);
    }
}

// ---- codebook -> 16x16x32-fragment image, wave-linear lane order ----
// A-frag: lane l holds e[code = base + (l&15)][k = ks*32+(l>>4)*8 ..+8]
// hi addr: IMG_OFF + ch*32768 + (ctg*4+ks)*1024 + ((l>>4)*16 + (l&15))*16; lo +16384
__global__ __launch_bounds__(256) void bconv_kernel(const float* __restrict__ embed,
                                                    char* __restrict__ ws) {
    int t    = blockIdx.x * 256 + threadIdx.x;   // 16384 threads
    int code = t >> 4;
    int seg  = t & 15;
    int ks   = seg >> 2;
    int kseg = seg & 3;
    int ch = code >> 6, ctg = (code >> 4) & 3, lr = code & 15;
    const float4* p = (const float4*)(embed + (size_t)code * Cdim + ks * 32 + kseg * 8);
    f16x8 h, lo;
    cvt8s(p[0], p[1], 1.0f, h, lo);
    size_t base = (size_t)IMG_OFF + (size_t)ch * CHUNK_BYTES
                + (ctg * 4 + ks) * 1024 + (kseg * 16 + lr) * 16;
    *(f16x8*)(ws + base)         = h;
    *(f16x8*)(ws + base + 16384) = lo;
}

// ---------------- async global->LDS 16B ----------------
__device__ __forceinline__ void gll16(const void* g, void* l) {
    __builtin_amdgcn_global_load_lds(
        (const __attribute__((address_space(1))) unsigned int*)g,
        (__attribute__((address_space(3))) unsigned int*)l, 16, 0, 0);
}

__global__ __launch_bounds__(THREADS, 2) void vq_kernel(
    const float* __restrict__ x, const float* __restrict__ embed,
    const char* __restrict__ ws, float* __restrict__ outq,
    float* __restrict__ outi) {

    __shared__ __align__(16) char  Bb[2][CHUNK_BYTES];   // 64KB dbuf
    __shared__ __align__(16) float esq_lds[KCODES];      // 4KB
    __shared__ float mrg_v[2][BROWS];
    __shared__ int   mrg_i[2][BROWS];
    __shared__ int   winners[BROWS];

    const int tid  = threadIdx.x;
    const int wid  = tid >> 6;          // wave 0..3
    const int l    = tid & 63;
    const int lr   = l & 15;            // x-row within 16-tile / code within frag
    const int lg   = l >> 4;            // k-seg (inputs) / code-subrow (outputs)
    const int wr   = wid & 1;           // row group (64 rows)
    const int nt   = wid >> 1;          // code half of each chunk
    const int row0 = blockIdx.x * BROWS;

    // ---- prologue DMA: chunk 0 (8KB/wave) + esq (1KB/wave) ----
    {
        const char* src = ws + IMG_OFF + wid * 8192 + (size_t)l * 16;
        char*       dst = &Bb[0][wid * 8192];
        #pragma unroll
        for (int i = 0; i < 8; ++i) gll16(src + i * 1024, dst + i * 1024);
        gll16(ws + wid * 1024 + (size_t)l * 16, (char*)esq_lds + wid * 1024);
    }

    // ---- x rows -> B-fragments (2*xh, 2*xl): bx[rt][ks], rows wr*64+rt*16+lr ----
    f16x8 bxh[4][4], bxl[4][4];
    #pragma unroll
    for (int rt = 0; rt < 4; ++rt) {
        const float* xr = x + (size_t)(row0 + wr * 64 + rt * 16 + lr) * Cdim + lg * 8;
        #pragma unroll
        for (int ks = 0; ks < 4; ++ks) {
            float4 v0 = *(const float4*)(xr + ks * 32);
            float4 v1 = *(const float4*)(xr + ks * 32 + 4);
            cvt8s(v0, v1, 2.0f, bxh[rt][ks], bxl[rt][ks]);
        }
    }

    float best[4];
    int   bidx[4];
    #pragma unroll
    for (int rt = 0; rt < 4; ++rt) { best[rt] = -FLT_MAX; bidx[rt] = 0; }

    #pragma unroll 1
    for (int ch = 0; ch < NCH; ++ch) {
        const int cur = ch & 1, nxt = cur ^ 1;

        __builtin_amdgcn_s_barrier();            // all done reading Bb[nxt]
        if (ch + 1 < NCH) {
            const char* src = ws + IMG_OFF + (size_t)(ch + 1) * CHUNK_BYTES
                            + wid * 8192 + (size_t)l * 16;
            char* dst = &Bb[nxt][wid * 8192];
            #pragma unroll
            for (int i = 0; i < 8; ++i) gll16(src + i * 1024, dst + i * 1024);
            asm volatile("s_waitcnt vmcnt(8)" ::: "memory");   // chunk ch staged
        } else {
            asm volatile("s_waitcnt vmcnt(0)" ::: "memory");
        }
        __builtin_amdgcn_s_barrier();            // chunk ch visible block-wide

        // 8 independent accumulator chains: acc[ct][rt]
        f32x4 acc[2][4];
        #pragma unroll
        for (int ct = 0; ct < 2; ++ct)
            #pragma unroll
            for (int rt = 0; rt < 4; ++rt)
                acc[ct][rt] = (f32x4){0.f, 0.f, 0.f, 0.f};

        const char* bb = &Bb[cur][(size_t)l * 16];

        #pragma unroll
        for (int ks = 0; ks < 4; ++ks) {
            // A-frags (codebook): identity lane pattern, conflict-free
            f16x8 eh0 = *(const f16x8*)(bb + ((nt * 2 + 0) * 4 + ks) * 1024);
            f16x8 el0 = *(const f16x8*)(bb + ((nt * 2 + 0) * 4 + ks) * 1024 + 16384);
            f16x8 eh1 = *(const f16x8*)(bb + ((nt * 2 + 1) * 4 + ks) * 1024);
            f16x8 el1 = *(const f16x8*)(bb + ((nt * 2 + 1) * 4 + ks) * 1024 + 16384);

            // pass 1: eh * 2xh   (same-acc reuse distance = 8 MFMAs)
            #pragma unroll
            for (int rt = 0; rt < 4; ++rt) acc[0][rt] = MFMA16(eh0, bxh[rt][ks], acc[0][rt]);
            #pragma unroll
            for (int rt = 0; rt < 4; ++rt) acc[1][rt] = MFMA16(eh1, bxh[rt][ks], acc[1][rt]);
            // pass 2: eh * 2xl
            #pragma unroll
            for (int rt = 0; rt < 4; ++rt) acc[0][rt] = MFMA16(eh0, bxl[rt][ks], acc[0][rt]);
            #pragma unroll
            for (int rt = 0; rt < 4; ++rt) acc[1][rt] = MFMA16(eh1, bxl[rt][ks], acc[1][rt]);
            // pass 3: el * 2xh
            #pragma unroll
            for (int rt = 0; rt < 4; ++rt) acc[0][rt] = MFMA16(el0, bxh[rt][ks], acc[0][rt]);
            #pragma unroll
            for (int rt = 0; rt < 4; ++rt) acc[1][rt] = MFMA16(el1, bxh[rt][ks], acc[1][rt]);
        }

        // scoring: s = 2*dot - e^2; pairwise index-aware merge tree (depth 4,
        // was 8 serial). Candidate order cb..cb+3 ascending; strict > keeps
        // the lower index on ties at every merge => exact first-index argmax.
        #pragma unroll
        for (int ct = 0; ct < 2; ++ct) {
            const int cb = ch * CH + (nt * 2 + ct) * 16 + lg * 4;
            float4 e4 = *(const float4*)&esq_lds[cb];
            #pragma unroll
            for (int rt = 0; rt < 4; ++rt) {
                float s0 = acc[ct][rt][0] - e4.x;
                float s1 = acc[ct][rt][1] - e4.y;
                float s2 = acc[ct][rt][2] - e4.z;
                float s3 = acc[ct][rt][3] - e4.w;
                float ta = s0; int ia = cb;
                if (s1 > ta) { ta = s1; ia = cb + 1; }
                float tb = s2; int ib = cb + 2;
                if (s3 > tb) { tb = s3; ib = cb + 3; }
                if (tb > ta) { ta = tb; ia = ib; }
                if (ta > best[rt]) { best[rt] = ta; bidx[rt] = ia; }
            }
        }
    }

    // ---- reduce over lg (lanes lr, lr+16, lr+32, lr+48 share each row) ----
    #pragma unroll
    for (int rt = 0; rt < 4; ++rt) {
        float bs = best[rt]; int bi = bidx[rt];
        #pragma unroll
        for (int m = 16; m <= 32; m <<= 1) {
            float vs = __shfl_xor(bs, m, 64);
            int   vi = __shfl_xor(bi, m, 64);
            if (vs > bs || (vs == bs && vi < bi)) { bs = vs; bi = vi; }
        }
        if (lg == 0) {
            mrg_v[nt][wr * 64 + rt * 16 + lr] = bs;
            mrg_i[nt][wr * 64 + rt * 16 + lr] = bi;
        }
    }
    __syncthreads();
    if (tid < BROWS) {
        float v0 = mrg_v[0][tid]; int i0 = mrg_i[0][tid];
        float v1 = mrg_v[1][tid]; int i1 = mrg_i[1][tid];
        int bi = (v1 > v0 || (v1 == v0 && i1 < i0)) ? i1 : i0;
        winners[tid] = bi;
        outi[row0 + tid] = (float)bi;
    }
    __syncthreads();

    // ---- gather quantized = embed[winner] (exact fp32 copy) ----
    #pragma unroll
    for (int i = 0; i < 16; ++i) {
        int pos = i * THREADS + tid;
        int r = pos >> 5, c4 = pos & 31;
        int idx = winners[r];
        float4 v = ((const float4*)(embed + (size_t)idx * Cdim))[c4];
        ((float4*)(outq + (size_t)(row0 + r) * Cdim))[c4] = v;
    }
}

extern "C" void kernel_launch(void* const* d_in, const int* in_sizes, int n_in,
                              void* d_out, int out_size, void* d_ws, size_t ws_size,
                              hipStream_t stream) {
    const float* x     = (const float*)d_in[0];
    const float* embed = (const float*)d_in[1];
    const int M = in_sizes[0] / Cdim;   // 65536
    const int K = in_sizes[1] / Cdim;   // 1024
    float* outq = (float*)d_out;
    float* outi = outq + (size_t)M * Cdim;

    esq_kernel <<<K / 4, 256, 0, stream>>>(embed, (float*)d_ws, K);
    bconv_kernel<<<64, 256, 0, stream>>>(embed, (char*)d_ws);
    vq_kernel  <<<M / BROWS, THREADS, 0, stream>>>(x, embed, (const char*)d_ws,
                                                   outq, outi);
}